// Round 9
// baseline (250.803 us; speedup 1.0000x reference)
//
#include <hip/hip_runtime.h>

#define D 512
#define DOUT 64
#define TAG (1 << 30)

typedef __bf16 bf16x8 __attribute__((ext_vector_type(8)));
typedef float floatx4 __attribute__((ext_vector_type(4)));

__device__ __forceinline__ bf16x8 cvt8f(float4 a0, float4 a1) {
    bf16x8 o;
    o[0] = (__bf16)a0.x; o[1] = (__bf16)a0.y; o[2] = (__bf16)a0.z; o[3] = (__bf16)a0.w;
    o[4] = (__bf16)a1.x; o[5] = (__bf16)a1.y; o[6] = (__bf16)a1.z; o[7] = (__bf16)a1.w;
    return o;
}

__device__ __forceinline__ int ld_acq(int* p) {
    return __hip_atomic_load(p, __ATOMIC_ACQUIRE, __HIP_MEMORY_SCOPE_AGENT);
}
__device__ __forceinline__ void st_rel(int* p, int v) {
    __hip_atomic_store(p, v, __ATOMIC_RELEASE, __HIP_MEMORY_SCOPE_AGENT);
}

// ---- GEMM1 (t = x @ W1^T, f32 inputs converted in-kernel) + degree histogram ----
// gemm blocks: m0=(b>>2)*128, n0=(b&3)*128 (N=K=512). hist blocks: grid-stride atomics.
__global__ __launch_bounds__(256) void gemm1_hist(
        const float* __restrict__ A, const float* __restrict__ Bw,
        __bf16* __restrict__ Cout, int M, int gemmBlocks,
        const int* __restrict__ dst, int* __restrict__ deg, int nE) {
    if (blockIdx.x >= gemmBlocks) {
        int base = (blockIdx.x - gemmBlocks) * 256 + threadIdx.x;
        int stride = (gridDim.x - gemmBlocks) * 256;
        for (int e = base; e < nE; e += stride) atomicAdd(&deg[dst[e]], 1);
        return;
    }
    constexpr int BM = 128, BN = 128, BK = 32;
    __shared__ __bf16 As[4 * BM * 8];   // granule P = kq*128 + row
    __shared__ __bf16 Bs[4 * BN * 8];

    const int tid = threadIdx.x;
    const int w = tid >> 6, lane = tid & 63;
    const int wrow = w >> 1, wcol = w & 1;
    const int m0 = (blockIdx.x >> 2) * BM, n0 = (blockIdx.x & 3) * BN;
    const int quad = lane >> 4, l15 = lane & 15;

    floatx4 acc[4][4] = {};

    for (int k0 = 0; k0 < D; k0 += BK) {
        #pragma unroll
        for (int gi = 0; gi < 2; ++gi) {
            int g = tid + gi * 256;          // 0..511
            int kq = g >> 7, row = g & 127;
            int ar = m0 + row; if (ar > M - 1) ar = M - 1;
            const float4* ap = (const float4*)(A + (size_t)ar * D + k0 + kq * 8);
            float4 a0 = ap[0], a1 = ap[1];
            const float4* bp = (const float4*)(Bw + (size_t)(n0 + row) * D + k0 + kq * 8);
            float4 b0 = bp[0], b1 = bp[1];
            *(bf16x8*)&As[(size_t)g * 8] = cvt8f(a0, a1);
            *(bf16x8*)&Bs[(size_t)g * 8] = cvt8f(b0, b1);
        }
        __syncthreads();

        bf16x8 af[4], bfr[4];
        #pragma unroll
        for (int mi = 0; mi < 4; ++mi)
            af[mi] = *(const bf16x8*)&As[(size_t)(quad * BM + wrow * 64 + mi * 16 + l15) * 8];
        #pragma unroll
        for (int nj = 0; nj < 4; ++nj)
            bfr[nj] = *(const bf16x8*)&Bs[(size_t)(quad * BN + wcol * 64 + nj * 16 + l15) * 8];
        #pragma unroll
        for (int mi = 0; mi < 4; ++mi)
            #pragma unroll
            for (int nj = 0; nj < 4; ++nj)
                acc[mi][nj] = __builtin_amdgcn_mfma_f32_16x16x32_bf16(
                    af[mi], bfr[nj], acc[mi][nj], 0, 0, 0);
        __syncthreads();
    }

    #pragma unroll
    for (int mi = 0; mi < 4; ++mi) {
        #pragma unroll
        for (int r = 0; r < 4; ++r) {
            int m = m0 + wrow * 64 + mi * 16 + quad * 4 + r;
            if (m < M) {
                #pragma unroll
                for (int nj = 0; nj < 4; ++nj) {
                    int n = n0 + wcol * 64 + nj * 16 + l15;
                    Cout[(size_t)m * D + n] = (__bf16)acc[mi][nj][r];
                }
            }
        }
    }
}

// ---- fused scan + fill: decoupled-lookback scan blocks, sleep-polling fill blocks ----
// blocks [0,SB): scan 1024 deg entries each, publish tagged sums, write rp+cursor, flag.
// blocks [SB,..): wait for all SB flags, then CSR bucket fill.
__global__ __launch_bounds__(256) void scanfill_kernel(
        const int* __restrict__ deg, int* __restrict__ rp, int* __restrict__ cursor,
        int* __restrict__ col, const int* __restrict__ src, const int* __restrict__ dst,
        int* __restrict__ prefix, int* __restrict__ sflag, int nN, int nE, int SB) {
    const int tid = threadIdx.x, b = blockIdx.x;
    const int lane = tid & 63, wid = tid >> 6;

    if (b < SB) {
        __shared__ int wtot[4];
        __shared__ int s_prev;
        int i4 = b * 1024 + tid * 4;
        int4 v = make_int4(0, 0, 0, 0);
        if (i4 + 3 < nN) v = *(const int4*)(deg + i4);
        else {
            if (i4 + 0 < nN) v.x = deg[i4 + 0];
            if (i4 + 1 < nN) v.y = deg[i4 + 1];
            if (i4 + 2 < nN) v.z = deg[i4 + 2];
        }
        int tsum = v.x + v.y + v.z + v.w;
        int s = tsum;
        #pragma unroll
        for (int off = 1; off < 64; off <<= 1) {
            int t = __shfl_up(s, off, 64);
            if (lane >= off) s += t;
        }
        if (lane == 63) wtot[wid] = s;
        __syncthreads();
        int woff = 0, btot = 0;
        #pragma unroll
        for (int i = 0; i < 4; ++i) {
            if (i < wid) woff += wtot[i];
            btot += wtot[i];
        }
        if (tid == 0) st_rel(&prefix[b], TAG | btot);
        // parallel lookback: thread j < b polls block j's total
        if (tid < 64) {
            int myv = 0;
            if (tid < b) {
                int vv;
                while (((vv = ld_acq(&prefix[tid])) & TAG) == 0)
                    __builtin_amdgcn_s_sleep(1);
                myv = vv & (TAG - 1);
            }
            #pragma unroll
            for (int off = 32; off >= 1; off >>= 1) myv += __shfl_xor(myv, off, 64);
            if (tid == 0) s_prev = myv;
        }
        __syncthreads();
        int prevsum = s_prev;
        int excl = prevsum + woff + (s - tsum);
        int4 o;
        o.x = excl; o.y = o.x + v.x; o.z = o.y + v.y; o.w = o.z + v.z;
        if (i4 + 3 < nN) {
            *(int4*)(rp + i4) = o;
            *(int4*)(cursor + i4) = o;
        } else {
            if (i4 + 0 < nN) { rp[i4 + 0] = o.x; cursor[i4 + 0] = o.x; }
            if (i4 + 1 < nN) { rp[i4 + 1] = o.y; cursor[i4 + 1] = o.y; }
            if (i4 + 2 < nN) { rp[i4 + 2] = o.z; cursor[i4 + 2] = o.z; }
        }
        if (tid == 0 && b == SB - 1) rp[nN] = prevsum + btot;
        __threadfence();         // per-thread: make cursor writes device-visible
        __syncthreads();
        if (tid == 0) st_rel(&sflag[b], TAG);
    } else {
        // fill block: wait for all scan flags
        if (tid < SB) {
            while ((ld_acq(&sflag[tid]) & TAG) == 0)
                __builtin_amdgcn_s_sleep(2);
        }
        __syncthreads();
        int e = (b - SB) * 256 + tid;
        if (e < nE) {
            int d = dst[e];
            int p = atomicAdd(&cursor[d], 1);
            col[p] = src[e];
        }
    }
}

// ---- fused: h2-rows = relu(S t) gathered into LDS, u = h2 @ W2^T (W2 f32 in-kernel) ----
// 16 nodes/block, 4 waves; ~20 KB LDS -> 8 blocks/CU for the latency-bound gather.
__global__ __launch_bounds__(256) void prop1_gemm2(
        const __bf16* __restrict__ t, const int* __restrict__ rp,
        const int* __restrict__ col, const float* __restrict__ W2f,
        __bf16* __restrict__ u, int nN) {
    __shared__ __bf16 As[16 * 512];    // granule P = r*64 + ((g+r)&63)
    __shared__ __bf16 Bs[4 * 64 * 8];  // granule P = kq*64 + n

    const int tid = threadIdx.x;
    const int w = tid >> 6, lane = tid & 63;
    const int quad = lane >> 4, l15 = lane & 15;
    const int m0 = blockIdx.x * 16;

    for (int r = w; r < 16; r += 4) {
        int n = m0 + r;
        float acc0[8] = {}, acc1[8] = {};
        if (n < nN) {
            int s0 = rp[n], s1 = rp[n + 1];
            int e = s0;
            for (; e + 4 <= s1; e += 4) {
                int sa = col[e], sb = col[e + 1], sc = col[e + 2], sd = col[e + 3];
                bf16x8 va = *(const bf16x8*)(t + (size_t)sa * D + lane * 8);
                bf16x8 vb = *(const bf16x8*)(t + (size_t)sb * D + lane * 8);
                bf16x8 vc = *(const bf16x8*)(t + (size_t)sc * D + lane * 8);
                bf16x8 vd = *(const bf16x8*)(t + (size_t)sd * D + lane * 8);
                #pragma unroll
                for (int i = 0; i < 8; ++i) {
                    acc0[i] += (float)va[i] + (float)vc[i];
                    acc1[i] += (float)vb[i] + (float)vd[i];
                }
            }
            for (; e < s1; ++e) {
                int sa = col[e];
                bf16x8 va = *(const bf16x8*)(t + (size_t)sa * D + lane * 8);
                #pragma unroll
                for (int i = 0; i < 8; ++i) acc0[i] += (float)va[i];
            }
        }
        bf16x8 o;
        #pragma unroll
        for (int i = 0; i < 8; ++i) o[i] = (__bf16)fmaxf(acc0[i] + acc1[i], 0.f);
        int P = r * 64 + ((lane + r) & 63);
        *(bf16x8*)&As[(size_t)P * 8] = o;
    }
    __syncthreads();

    floatx4 acc = {};
    for (int k0 = 0; k0 < D; k0 += 32) {
        // stage W2 chunk (f32 -> bf16): granule tid = kq(w)*64 + n(lane)
        const float4* bp = (const float4*)(W2f + (size_t)lane * D + k0 + w * 8);
        float4 b0 = bp[0], b1 = bp[1];
        *(bf16x8*)&Bs[(size_t)tid * 8] = cvt8f(b0, b1);
        __syncthreads();
        int g = (k0 >> 3) + quad;
        bf16x8 af = *(const bf16x8*)&As[(size_t)(l15 * 64 + ((g + l15) & 63)) * 8];
        bf16x8 bfr = *(const bf16x8*)&Bs[(size_t)(quad * 64 + w * 16 + l15) * 8];
        acc = __builtin_amdgcn_mfma_f32_16x16x32_bf16(af, bfr, acc, 0, 0, 0);
        __syncthreads();
    }

    #pragma unroll
    for (int r = 0; r < 4; ++r) {
        int m = m0 + quad * 4 + r;
        if (m < nN)
            u[(size_t)m * DOUT + w * 16 + l15] = (__bf16)acc[r];
    }
}

// ---- propagate 64-wide + log_softmax fused: wave per node, lane = output col ----
__global__ __launch_bounds__(256) void prop2_lsm(const __bf16* __restrict__ u,
        const int* __restrict__ rp, const int* __restrict__ col,
        float* __restrict__ out, int nN) {
    int n = blockIdx.x * 4 + (threadIdx.x >> 6);
    if (n >= nN) return;
    int lane = threadIdx.x & 63;
    int s0 = rp[n], s1 = rp[n + 1];
    float a0 = 0.f, a1 = 0.f, a2 = 0.f, a3 = 0.f;
    int e = s0;
    for (; e + 4 <= s1; e += 4) {
        int sa = col[e], sb = col[e + 1], sc = col[e + 2], sd = col[e + 3];
        a0 += (float)u[(size_t)sa * DOUT + lane];
        a1 += (float)u[(size_t)sb * DOUT + lane];
        a2 += (float)u[(size_t)sc * DOUT + lane];
        a3 += (float)u[(size_t)sd * DOUT + lane];
    }
    for (; e < s1; ++e) a0 += (float)u[(size_t)col[e] * DOUT + lane];
    float v = (a0 + a2) + (a1 + a3);
    float mx = v;
    #pragma unroll
    for (int off = 32; off >= 1; off >>= 1) mx = fmaxf(mx, __shfl_xor(mx, off, 64));
    float s = expf(v - mx);
    #pragma unroll
    for (int off = 32; off >= 1; off >>= 1) s += __shfl_xor(s, off, 64);
    out[(size_t)n * DOUT + lane] = v - mx - logf(s);
}

// ---------------- launch ----------------

extern "C" void kernel_launch(void* const* d_in, const int* in_sizes, int n_in,
                              void* d_out, int out_size, void* d_ws, size_t ws_size,
                              hipStream_t stream) {
    const float* x  = (const float*)d_in[0];
    const int*   ei = (const int*)d_in[1];
    const float* W1 = (const float*)d_in[2];
    const float* W2 = (const float*)d_in[3];
    float* out = (float*)d_out;

    const int N = in_sizes[0] / D;   // 20000
    const int E = in_sizes[1] / 2;   // 160000
    const int* src = ei;
    const int* dst = ei + E;
    const int SB = (N + 1023) / 1024;

    size_t off = 0;
    auto alloc = [&](size_t bytes) -> void* {
        void* p = (char*)d_ws + off;
        off = (off + bytes + 255) & ~(size_t)255;
        return p;
    };
    int*    meta    = (int*)alloc(sizeof(int) * (size_t)(N + 2 * SB));
    int*    deg     = meta;
    int*    prefix  = meta + N;
    int*    sflag   = meta + N + SB;
    int*    row_ptr = (int*)alloc(sizeof(int) * (size_t)(N + 1));
    int*    cursor  = (int*)alloc(sizeof(int) * (size_t)N);
    int*    col     = (int*)alloc(sizeof(int) * (size_t)E);
    __bf16* t       = (__bf16*)alloc(sizeof(__bf16) * (size_t)N * D);    // x@W1^T
    __bf16* u       = (__bf16*)alloc(sizeof(__bf16) * (size_t)N * DOUT); // relu(S t)@W2^T

    // 1) zero deg + scan/fill flags (tiny driver fill)
    hipMemsetAsync(meta, 0, sizeof(int) * (size_t)(N + 2 * SB), stream);

    // 2) t = x @ W1^T (in-kernel f32->bf16) + degree histogram
    const int gemmBlocks = ((N + 127) / 128) * 4;
    gemm1_hist<<<gemmBlocks + 64, 256, 0, stream>>>(x, W1, t, N, gemmBlocks, dst, deg, E);

    // 3) fused scan + CSR fill (decoupled lookback + polling fill blocks)
    const int fillBlocks = (E + 255) / 256;
    scanfill_kernel<<<SB + fillBlocks, 256, 0, stream>>>(
        deg, row_ptr, cursor, col, src, dst, prefix, sflag, N, E, SB);

    // 4) u = relu(S t) @ W2^T  (fused gather + small GEMM, W2 converted in-kernel)
    prop1_gemm2<<<(N + 15) / 16, 256, 0, stream>>>(t, row_ptr, col, W2, u, N);

    // 5) out = lsm(S u)
    prop2_lsm<<<(N + 3) / 4, 256, 0, stream>>>(u, row_ptr, col, out, N);
}

// Round 10
// 211.969 us; speedup vs baseline: 1.1832x; 1.1832x over previous
//
#include <hip/hip_runtime.h>

#define D 512
#define DOUT 64
#define TAG (1 << 30)

typedef __bf16 bf16x8 __attribute__((ext_vector_type(8)));
typedef float floatx4 __attribute__((ext_vector_type(4)));

__device__ __forceinline__ void async_cp16(const void* g, void* lds) {
    __builtin_amdgcn_global_load_lds(
        (__attribute__((address_space(1))) void*)(void*)g,
        (__attribute__((address_space(3))) void*)lds, 16, 0, 0);
}

__device__ __forceinline__ int ld_acq(int* p) {
    return __hip_atomic_load(p, __ATOMIC_ACQUIRE, __HIP_MEMORY_SCOPE_AGENT);
}
__device__ __forceinline__ void st_rel(int* p, int v) {
    __hip_atomic_store(p, v, __ATOMIC_RELEASE, __HIP_MEMORY_SCOPE_AGENT);
}

// ---- prep: zero deg/flags + 3 f32->bf16 conversions, partitioned by blockIdx ----
__global__ __launch_bounds__(256) void prep_kernel(
        int* __restrict__ meta, int nMeta, int zeroBlocks,
        const float* __restrict__ x, __bf16* __restrict__ xb, int xN8,
        const float* __restrict__ W1, __bf16* __restrict__ w1b, int w1N8,
        const float* __restrict__ W2, __bf16* __restrict__ w2b, int w2N8) {
    int b = blockIdx.x;
    if (b < zeroBlocks) {
        int i4 = b * 1024 + threadIdx.x * 4;
        if (i4 + 3 < nMeta) *(int4*)(meta + i4) = make_int4(0, 0, 0, 0);
        else {
            if (i4 + 0 < nMeta) meta[i4 + 0] = 0;
            if (i4 + 1 < nMeta) meta[i4 + 1] = 0;
            if (i4 + 2 < nMeta) meta[i4 + 2] = 0;
        }
        return;
    }
    b -= zeroBlocks;
    int xBlocks = (xN8 + 255) >> 8;
    int w1Blocks = (w1N8 + 255) >> 8;
    const float* in; __bf16* outp; int n8;
    if (b < xBlocks) { in = x; outp = xb; n8 = xN8; }
    else if (b < xBlocks + w1Blocks) { b -= xBlocks; in = W1; outp = w1b; n8 = w1N8; }
    else { b -= xBlocks + w1Blocks; in = W2; outp = w2b; n8 = w2N8; }
    int i = b * 256 + threadIdx.x;
    if (i < n8) {
        const float4* p = (const float4*)in + (size_t)i * 2;
        float4 v0 = p[0], v1 = p[1];
        bf16x8 o;
        o[0] = (__bf16)v0.x; o[1] = (__bf16)v0.y; o[2] = (__bf16)v0.z; o[3] = (__bf16)v0.w;
        o[4] = (__bf16)v1.x; o[5] = (__bf16)v1.y; o[6] = (__bf16)v1.z; o[7] = (__bf16)v1.w;
        *((bf16x8*)outp + i) = o;
    }
}

// ---- GEMM1 (t = xb @ W1^T, bf16, global_load_lds staging) + degree histogram ----
__global__ __launch_bounds__(256) void gemm1_hist(
        const __bf16* __restrict__ A, const __bf16* __restrict__ B,
        __bf16* __restrict__ Cout, int M, int gemmBlocks,
        const int* __restrict__ dst, int* __restrict__ deg, int nE) {
    if (blockIdx.x >= gemmBlocks) {
        int base = (blockIdx.x - gemmBlocks) * 256 + threadIdx.x;
        int stride = (gridDim.x - gemmBlocks) * 256;
        for (int e = base; e < nE; e += stride) atomicAdd(&deg[dst[e]], 1);
        return;
    }
    constexpr int BM = 128, BN = 128, BK = 32;
    constexpr int CPA = 2, CPB = 2;
    __shared__ __bf16 As[4 * BM * 8];
    __shared__ __bf16 Bs[4 * BN * 8];

    const int tid = threadIdx.x;
    const int w = tid >> 6, lane = tid & 63;
    const int wrow = w >> 1, wcol = w & 1;
    const int m0 = (blockIdx.x >> 2) * BM, n0 = (blockIdx.x & 3) * BN;
    const int quad = lane >> 4, l15 = lane & 15;

    floatx4 acc[4][4] = {};

    for (int k0 = 0; k0 < D; k0 += BK) {
        #pragma unroll
        for (int c = 0; c < CPA; ++c) {
            int ca = w * CPA + c;
            int kq = ca / CPA;
            int row = m0 + (ca % CPA) * 64 + lane;
            if (row > M - 1) row = M - 1;
            async_cp16(A + (size_t)row * D + k0 + kq * 8, &As[(size_t)ca * 512]);
        }
        #pragma unroll
        for (int c = 0; c < CPB; ++c) {
            int cb = w * CPB + c;
            int kq = cb / CPB;
            int nn = n0 + (cb % CPB) * 64 + lane;
            async_cp16(B + (size_t)nn * D + k0 + kq * 8, &Bs[(size_t)cb * 512]);
        }
        __syncthreads();

        bf16x8 af[4], bfr[4];
        #pragma unroll
        for (int mi = 0; mi < 4; ++mi)
            af[mi] = *(const bf16x8*)&As[(size_t)(quad * BM + wrow * 64 + mi * 16 + l15) * 8];
        #pragma unroll
        for (int nj = 0; nj < 4; ++nj)
            bfr[nj] = *(const bf16x8*)&Bs[(size_t)(quad * BN + wcol * 64 + nj * 16 + l15) * 8];
        #pragma unroll
        for (int mi = 0; mi < 4; ++mi)
            #pragma unroll
            for (int nj = 0; nj < 4; ++nj)
                acc[mi][nj] = __builtin_amdgcn_mfma_f32_16x16x32_bf16(
                    af[mi], bfr[nj], acc[mi][nj], 0, 0, 0);
        __syncthreads();
    }

    #pragma unroll
    for (int mi = 0; mi < 4; ++mi) {
        #pragma unroll
        for (int r = 0; r < 4; ++r) {
            int m = m0 + wrow * 64 + mi * 16 + quad * 4 + r;
            if (m < M) {
                #pragma unroll
                for (int nj = 0; nj < 4; ++nj) {
                    int n = n0 + wcol * 64 + nj * 16 + l15;
                    Cout[(size_t)m * D + n] = (__bf16)acc[mi][nj][r];
                }
            }
        }
    }
}

// ---- fused scan + fill: decoupled-lookback scan blocks, sleep-polling fill blocks ----
__global__ __launch_bounds__(256) void scanfill_kernel(
        const int* __restrict__ deg, int* __restrict__ rp, int* __restrict__ cursor,
        int* __restrict__ col, const int* __restrict__ src, const int* __restrict__ dst,
        int* __restrict__ prefix, int* __restrict__ sflag, int nN, int nE, int SB) {
    const int tid = threadIdx.x, b = blockIdx.x;
    const int lane = tid & 63, wid = tid >> 6;

    if (b < SB) {
        __shared__ int wtot[4];
        __shared__ int s_prev;
        int i4 = b * 1024 + tid * 4;
        int4 v = make_int4(0, 0, 0, 0);
        if (i4 + 3 < nN) v = *(const int4*)(deg + i4);
        else {
            if (i4 + 0 < nN) v.x = deg[i4 + 0];
            if (i4 + 1 < nN) v.y = deg[i4 + 1];
            if (i4 + 2 < nN) v.z = deg[i4 + 2];
        }
        int tsum = v.x + v.y + v.z + v.w;
        int s = tsum;
        #pragma unroll
        for (int off = 1; off < 64; off <<= 1) {
            int t = __shfl_up(s, off, 64);
            if (lane >= off) s += t;
        }
        if (lane == 63) wtot[wid] = s;
        __syncthreads();
        int woff = 0, btot = 0;
        #pragma unroll
        for (int i = 0; i < 4; ++i) {
            if (i < wid) woff += wtot[i];
            btot += wtot[i];
        }
        if (tid == 0) st_rel(&prefix[b], TAG | btot);
        if (tid < 64) {
            int myv = 0;
            if (tid < b) {
                int vv;
                while (((vv = ld_acq(&prefix[tid])) & TAG) == 0)
                    __builtin_amdgcn_s_sleep(1);
                myv = vv & (TAG - 1);
            }
            #pragma unroll
            for (int off = 32; off >= 1; off >>= 1) myv += __shfl_xor(myv, off, 64);
            if (tid == 0) s_prev = myv;
        }
        __syncthreads();
        int prevsum = s_prev;
        int excl = prevsum + woff + (s - tsum);
        int4 o;
        o.x = excl; o.y = o.x + v.x; o.z = o.y + v.y; o.w = o.z + v.z;
        if (i4 + 3 < nN) {
            *(int4*)(rp + i4) = o;
            *(int4*)(cursor + i4) = o;
        } else {
            if (i4 + 0 < nN) { rp[i4 + 0] = o.x; cursor[i4 + 0] = o.x; }
            if (i4 + 1 < nN) { rp[i4 + 1] = o.y; cursor[i4 + 1] = o.y; }
            if (i4 + 2 < nN) { rp[i4 + 2] = o.z; cursor[i4 + 2] = o.z; }
        }
        if (tid == 0 && b == SB - 1) rp[nN] = prevsum + btot;
        __threadfence();
        __syncthreads();
        if (tid == 0) st_rel(&sflag[b], TAG);
    } else {
        if (tid < SB) {
            while ((ld_acq(&sflag[tid]) & TAG) == 0)
                __builtin_amdgcn_s_sleep(2);
        }
        __syncthreads();
        int e = (b - SB) * 256 + tid;
        if (e < nE) {
            int d = dst[e];
            int p = atomicAdd(&cursor[d], 1);
            col[p] = src[e];
        }
    }
}

// ---- fused: h2-rows = relu(S t) gathered into LDS, u = h2 @ W2^T (bf16 out) ----
// 16 nodes/block, 4 waves; ~20 KB LDS -> 8 blocks/CU for the latency-bound gather.
__global__ __launch_bounds__(256) void prop1_gemm2(
        const __bf16* __restrict__ t, const int* __restrict__ rp,
        const int* __restrict__ col, const __bf16* __restrict__ B,
        __bf16* __restrict__ u, int nN) {
    __shared__ __bf16 As[16 * 512];    // granule P = r*64 + ((g+r)&63)
    __shared__ __bf16 Bs[4 * 64 * 8];  // granule P = kq*64 + n

    const int tid = threadIdx.x;
    const int w = tid >> 6, lane = tid & 63;
    const int quad = lane >> 4, l15 = lane & 15;
    const int m0 = blockIdx.x * 16;

    for (int r = w; r < 16; r += 4) {
        int n = m0 + r;
        float acc0[8] = {}, acc1[8] = {};
        if (n < nN) {
            int s0 = rp[n], s1 = rp[n + 1];
            int e = s0;
            for (; e + 4 <= s1; e += 4) {
                int sa = col[e], sb = col[e + 1], sc = col[e + 2], sd = col[e + 3];
                bf16x8 va = *(const bf16x8*)(t + (size_t)sa * D + lane * 8);
                bf16x8 vb = *(const bf16x8*)(t + (size_t)sb * D + lane * 8);
                bf16x8 vc = *(const bf16x8*)(t + (size_t)sc * D + lane * 8);
                bf16x8 vd = *(const bf16x8*)(t + (size_t)sd * D + lane * 8);
                #pragma unroll
                for (int i = 0; i < 8; ++i) {
                    acc0[i] += (float)va[i] + (float)vc[i];
                    acc1[i] += (float)vb[i] + (float)vd[i];
                }
            }
            for (; e < s1; ++e) {
                int sa = col[e];
                bf16x8 va = *(const bf16x8*)(t + (size_t)sa * D + lane * 8);
                #pragma unroll
                for (int i = 0; i < 8; ++i) acc0[i] += (float)va[i];
            }
        }
        bf16x8 o;
        #pragma unroll
        for (int i = 0; i < 8; ++i) o[i] = (__bf16)fmaxf(acc0[i] + acc1[i], 0.f);
        int P = r * 64 + ((lane + r) & 63);
        *(bf16x8*)&As[(size_t)P * 8] = o;
    }
    __syncthreads();

    floatx4 acc = {};
    for (int k0 = 0; k0 < D; k0 += 32) {
        async_cp16(B + (size_t)lane * D + k0 + w * 8, &Bs[(size_t)w * 512]);
        __syncthreads();
        int g = (k0 >> 3) + quad;
        bf16x8 af = *(const bf16x8*)&As[(size_t)(l15 * 64 + ((g + l15) & 63)) * 8];
        bf16x8 bfr = *(const bf16x8*)&Bs[(size_t)(quad * 64 + w * 16 + l15) * 8];
        acc = __builtin_amdgcn_mfma_f32_16x16x32_bf16(af, bfr, acc, 0, 0, 0);
        __syncthreads();
    }

    #pragma unroll
    for (int r = 0; r < 4; ++r) {
        int m = m0 + quad * 4 + r;
        if (m < nN)
            u[(size_t)m * DOUT + w * 16 + l15] = (__bf16)acc[r];
    }
}

// ---- propagate 64-wide + log_softmax fused: wave per node, lane = output col ----
__global__ __launch_bounds__(256) void prop2_lsm(const __bf16* __restrict__ u,
        const int* __restrict__ rp, const int* __restrict__ col,
        float* __restrict__ out, int nN) {
    int n = blockIdx.x * 4 + (threadIdx.x >> 6);
    if (n >= nN) return;
    int lane = threadIdx.x & 63;
    int s0 = rp[n], s1 = rp[n + 1];
    float a0 = 0.f, a1 = 0.f, a2 = 0.f, a3 = 0.f;
    int e = s0;
    for (; e + 4 <= s1; e += 4) {
        int sa = col[e], sb = col[e + 1], sc = col[e + 2], sd = col[e + 3];
        a0 += (float)u[(size_t)sa * DOUT + lane];
        a1 += (float)u[(size_t)sb * DOUT + lane];
        a2 += (float)u[(size_t)sc * DOUT + lane];
        a3 += (float)u[(size_t)sd * DOUT + lane];
    }
    for (; e < s1; ++e) a0 += (float)u[(size_t)col[e] * DOUT + lane];
    float v = (a0 + a2) + (a1 + a3);
    float mx = v;
    #pragma unroll
    for (int off = 32; off >= 1; off >>= 1) mx = fmaxf(mx, __shfl_xor(mx, off, 64));
    float s = expf(v - mx);
    #pragma unroll
    for (int off = 32; off >= 1; off >>= 1) s += __shfl_xor(s, off, 64);
    out[(size_t)n * DOUT + lane] = v - mx - logf(s);
}

// ---------------- launch ----------------

extern "C" void kernel_launch(void* const* d_in, const int* in_sizes, int n_in,
                              void* d_out, int out_size, void* d_ws, size_t ws_size,
                              hipStream_t stream) {
    const float* x  = (const float*)d_in[0];
    const int*   ei = (const int*)d_in[1];
    const float* W1 = (const float*)d_in[2];
    const float* W2 = (const float*)d_in[3];
    float* out = (float*)d_out;

    const int N = in_sizes[0] / D;   // 20000
    const int E = in_sizes[1] / 2;   // 160000
    const int* src = ei;
    const int* dst = ei + E;
    const int SB = (N + 1023) / 1024;

    size_t off = 0;
    auto alloc = [&](size_t bytes) -> void* {
        void* p = (char*)d_ws + off;
        off = (off + bytes + 255) & ~(size_t)255;
        return p;
    };
    const int nMeta = N + 2 * SB;
    int*    meta    = (int*)alloc(sizeof(int) * (size_t)nMeta);
    int*    deg     = meta;
    int*    prefix  = meta + N;
    int*    sflag   = meta + N + SB;
    int*    row_ptr = (int*)alloc(sizeof(int) * (size_t)(N + 1));
    int*    cursor  = (int*)alloc(sizeof(int) * (size_t)N);
    int*    col     = (int*)alloc(sizeof(int) * (size_t)E);
    __bf16* w1b     = (__bf16*)alloc(sizeof(__bf16) * (size_t)D * D);
    __bf16* w2b     = (__bf16*)alloc(sizeof(__bf16) * (size_t)DOUT * D);
    __bf16* xb      = (__bf16*)alloc(sizeof(__bf16) * (size_t)N * D);
    __bf16* t       = (__bf16*)alloc(sizeof(__bf16) * (size_t)N * D);    // x@W1^T
    __bf16* u       = (__bf16*)alloc(sizeof(__bf16) * (size_t)N * DOUT); // relu(S t)@W2^T

    const int zeroBlocks = (nMeta + 1023) / 1024;
    const int xN8 = N * D / 8, w1N8 = D * D / 8, w2N8 = DOUT * D / 8;
    const int cvtBlocks = (xN8 + 255) / 256 + (w1N8 + 255) / 256 + (w2N8 + 255) / 256;

    // 1) prep: zero meta + bf16 conversions
    prep_kernel<<<zeroBlocks + cvtBlocks, 256, 0, stream>>>(
        meta, nMeta, zeroBlocks, x, xb, xN8, W1, w1b, w1N8, W2, w2b, w2N8);

    // 2) t = xb @ W1^T (async LDS staging) + degree histogram
    const int gemmBlocks = ((N + 127) / 128) * 4;
    gemm1_hist<<<gemmBlocks + 64, 256, 0, stream>>>(
        xb, w1b, t, N, gemmBlocks, dst, deg, E);

    // 3) fused scan + CSR fill
    const int fillBlocks = (E + 255) / 256;
    scanfill_kernel<<<SB + fillBlocks, 256, 0, stream>>>(
        deg, row_ptr, cursor, col, src, dst, prefix, sflag, N, E, SB);

    // 4) u = relu(S t) @ W2^T
    prop1_gemm2<<<(N + 15) / 16, 256, 0, stream>>>(t, row_ptr, col, w2b, u, N);

    // 5) out = lsm(S u)
    prop2_lsm<<<(N + 3) / 4, 256, 0, stream>>>(u, row_ptr, col, out, N);
}

// Round 11
// 209.074 us; speedup vs baseline: 1.1996x; 1.0138x over previous
//
#include <hip/hip_runtime.h>

#define D 512
#define DOUT 64
#define TAG (1 << 30)

typedef __bf16 bf16x8 __attribute__((ext_vector_type(8)));
typedef float floatx4 __attribute__((ext_vector_type(4)));

__device__ __forceinline__ void async_cp16(const void* g, void* lds) {
    __builtin_amdgcn_global_load_lds(
        (__attribute__((address_space(1))) void*)(void*)g,
        (__attribute__((address_space(3))) void*)lds, 16, 0, 0);
}

__device__ __forceinline__ int ld_acq(int* p) {
    return __hip_atomic_load(p, __ATOMIC_ACQUIRE, __HIP_MEMORY_SCOPE_AGENT);
}
__device__ __forceinline__ void st_rel(int* p, int v) {
    __hip_atomic_store(p, v, __ATOMIC_RELEASE, __HIP_MEMORY_SCOPE_AGENT);
}

// ---- prep: zero deg/prefix/done + 3 f32->bf16 conversions ----
__global__ __launch_bounds__(256) void prep_kernel(
        int* __restrict__ meta, int nMeta, int zeroBlocks,
        const float* __restrict__ x, __bf16* __restrict__ xb, int xN8,
        const float* __restrict__ W1, __bf16* __restrict__ w1b, int w1N8,
        const float* __restrict__ W2, __bf16* __restrict__ w2b, int w2N8) {
    int b = blockIdx.x;
    if (b < zeroBlocks) {
        int i4 = b * 1024 + threadIdx.x * 4;
        if (i4 + 3 < nMeta) *(int4*)(meta + i4) = make_int4(0, 0, 0, 0);
        else {
            if (i4 + 0 < nMeta) meta[i4 + 0] = 0;
            if (i4 + 1 < nMeta) meta[i4 + 1] = 0;
            if (i4 + 2 < nMeta) meta[i4 + 2] = 0;
        }
        return;
    }
    b -= zeroBlocks;
    int xBlocks = (xN8 + 255) >> 8;
    int w1Blocks = (w1N8 + 255) >> 8;
    const float* in; __bf16* outp; int n8;
    if (b < xBlocks) { in = x; outp = xb; n8 = xN8; }
    else if (b < xBlocks + w1Blocks) { b -= xBlocks; in = W1; outp = w1b; n8 = w1N8; }
    else { b -= xBlocks + w1Blocks; in = W2; outp = w2b; n8 = w2N8; }
    int i = b * 256 + threadIdx.x;
    if (i < n8) {
        const float4* p = (const float4*)in + (size_t)i * 2;
        float4 v0 = p[0], v1 = p[1];
        bf16x8 o;
        o[0] = (__bf16)v0.x; o[1] = (__bf16)v0.y; o[2] = (__bf16)v0.z; o[3] = (__bf16)v0.w;
        o[4] = (__bf16)v1.x; o[5] = (__bf16)v1.y; o[6] = (__bf16)v1.z; o[7] = (__bf16)v1.w;
        *((bf16x8*)outp + i) = o;
    }
}

// ---- GEMM1 (t = xb @ W1^T, bf16, global_load_lds staging) + degree histogram ----
__global__ __launch_bounds__(256) void gemm1_hist(
        const __bf16* __restrict__ A, const __bf16* __restrict__ B,
        __bf16* __restrict__ Cout, int M, int gemmBlocks,
        const int* __restrict__ dst, int* __restrict__ deg, int nE) {
    if (blockIdx.x >= gemmBlocks) {
        int base = (blockIdx.x - gemmBlocks) * 256 + threadIdx.x;
        int stride = (gridDim.x - gemmBlocks) * 256;
        for (int e = base; e < nE; e += stride) atomicAdd(&deg[dst[e]], 1);
        return;
    }
    constexpr int BM = 128, BN = 128, BK = 32;
    constexpr int CPA = 2, CPB = 2;
    __shared__ __bf16 As[4 * BM * 8];
    __shared__ __bf16 Bs[4 * BN * 8];

    const int tid = threadIdx.x;
    const int w = tid >> 6, lane = tid & 63;
    const int wrow = w >> 1, wcol = w & 1;
    const int m0 = (blockIdx.x >> 2) * BM, n0 = (blockIdx.x & 3) * BN;
    const int quad = lane >> 4, l15 = lane & 15;

    floatx4 acc[4][4] = {};

    for (int k0 = 0; k0 < D; k0 += BK) {
        #pragma unroll
        for (int c = 0; c < CPA; ++c) {
            int ca = w * CPA + c;
            int kq = ca / CPA;
            int row = m0 + (ca % CPA) * 64 + lane;
            if (row > M - 1) row = M - 1;
            async_cp16(A + (size_t)row * D + k0 + kq * 8, &As[(size_t)ca * 512]);
        }
        #pragma unroll
        for (int c = 0; c < CPB; ++c) {
            int cb = w * CPB + c;
            int kq = cb / CPB;
            int nn = n0 + (cb % CPB) * 64 + lane;
            async_cp16(B + (size_t)nn * D + k0 + kq * 8, &Bs[(size_t)cb * 512]);
        }
        __syncthreads();

        bf16x8 af[4], bfr[4];
        #pragma unroll
        for (int mi = 0; mi < 4; ++mi)
            af[mi] = *(const bf16x8*)&As[(size_t)(quad * BM + wrow * 64 + mi * 16 + l15) * 8];
        #pragma unroll
        for (int nj = 0; nj < 4; ++nj)
            bfr[nj] = *(const bf16x8*)&Bs[(size_t)(quad * BN + wcol * 64 + nj * 16 + l15) * 8];
        #pragma unroll
        for (int mi = 0; mi < 4; ++mi)
            #pragma unroll
            for (int nj = 0; nj < 4; ++nj)
                acc[mi][nj] = __builtin_amdgcn_mfma_f32_16x16x32_bf16(
                    af[mi], bfr[nj], acc[mi][nj], 0, 0, 0);
        __syncthreads();
    }

    #pragma unroll
    for (int mi = 0; mi < 4; ++mi) {
        #pragma unroll
        for (int r = 0; r < 4; ++r) {
            int m = m0 + wrow * 64 + mi * 16 + quad * 4 + r;
            if (m < M) {
                #pragma unroll
                for (int nj = 0; nj < 4; ++nj) {
                    int n = n0 + wcol * 64 + nj * 16 + l15;
                    Cout[(size_t)m * D + n] = (__bf16)acc[mi][nj][r];
                }
            }
        }
    }
}

// ---- fused scan + fill: lookback scan blocks; fill blocks poll ONE counter ----
__global__ __launch_bounds__(256) void scanfill_kernel(
        const int* __restrict__ deg, int* __restrict__ rp, int* __restrict__ cursor,
        int* __restrict__ col, const int* __restrict__ src, const int* __restrict__ dst,
        int* __restrict__ prefix, int* __restrict__ done, int nN, int nE, int SB) {
    const int tid = threadIdx.x, b = blockIdx.x;
    const int lane = tid & 63, wid = tid >> 6;

    if (b < SB) {
        __shared__ int wtot[4];
        __shared__ int s_prev;
        int i4 = b * 1024 + tid * 4;
        int4 v = make_int4(0, 0, 0, 0);
        if (i4 + 3 < nN) v = *(const int4*)(deg + i4);
        else {
            if (i4 + 0 < nN) v.x = deg[i4 + 0];
            if (i4 + 1 < nN) v.y = deg[i4 + 1];
            if (i4 + 2 < nN) v.z = deg[i4 + 2];
        }
        int tsum = v.x + v.y + v.z + v.w;
        int s = tsum;
        #pragma unroll
        for (int off = 1; off < 64; off <<= 1) {
            int t = __shfl_up(s, off, 64);
            if (lane >= off) s += t;
        }
        if (lane == 63) wtot[wid] = s;
        __syncthreads();
        int woff = 0, btot = 0;
        #pragma unroll
        for (int i = 0; i < 4; ++i) {
            if (i < wid) woff += wtot[i];
            btot += wtot[i];
        }
        if (tid == 0) st_rel(&prefix[b], TAG | btot);
        if (tid < 64) {
            int myv = 0;
            if (tid < b) {
                int vv;
                while (((vv = ld_acq(&prefix[tid])) & TAG) == 0)
                    __builtin_amdgcn_s_sleep(1);
                myv = vv & (TAG - 1);
            }
            #pragma unroll
            for (int off = 32; off >= 1; off >>= 1) myv += __shfl_xor(myv, off, 64);
            if (tid == 0) s_prev = myv;
        }
        __syncthreads();
        int prevsum = s_prev;
        int excl = prevsum + woff + (s - tsum);
        int4 o;
        o.x = excl; o.y = o.x + v.x; o.z = o.y + v.y; o.w = o.z + v.z;
        if (i4 + 3 < nN) {
            *(int4*)(rp + i4) = o;
            *(int4*)(cursor + i4) = o;
        } else {
            if (i4 + 0 < nN) { rp[i4 + 0] = o.x; cursor[i4 + 0] = o.x; }
            if (i4 + 1 < nN) { rp[i4 + 1] = o.y; cursor[i4 + 1] = o.y; }
            if (i4 + 2 < nN) { rp[i4 + 2] = o.z; cursor[i4 + 2] = o.z; }
        }
        if (tid == 0 && b == SB - 1) rp[nN] = prevsum + btot;
        __threadfence();              // drain cursor/rp writes to device scope
        __syncthreads();
        if (tid == 0) atomicAdd(done, 1);   // device-scope signal, one per block
    } else {
        // fill block: ONE lane polls ONE counter with long sleeps (no contention)
        if (tid == 0) {
            while (ld_acq(done) < SB)
                __builtin_amdgcn_s_sleep(64);   // ~1.7 us between polls
        }
        __syncthreads();
        int e = (b - SB) * 256 + tid;
        if (e < nE) {
            int d = dst[e];
            int p = atomicAdd(&cursor[d], 1);
            col[p] = src[e];
        }
    }
}

// ---- fused: h2-rows = relu(S t) gathered into LDS, u = h2 @ W2^T (bf16 out) ----
// 16 nodes/block, 4 waves; ~20 KB LDS -> 8 blocks/CU for the latency-bound gather.
__global__ __launch_bounds__(256) void prop1_gemm2(
        const __bf16* __restrict__ t, const int* __restrict__ rp,
        const int* __restrict__ col, const __bf16* __restrict__ B,
        __bf16* __restrict__ u, int nN) {
    __shared__ __bf16 As[16 * 512];    // granule P = r*64 + ((g+r)&63)
    __shared__ __bf16 Bs[4 * 64 * 8];  // granule P = kq*64 + n

    const int tid = threadIdx.x;
    const int w = tid >> 6, lane = tid & 63;
    const int quad = lane >> 4, l15 = lane & 15;
    const int m0 = blockIdx.x * 16;

    for (int r = w; r < 16; r += 4) {
        int n = m0 + r;
        float acc0[8] = {}, acc1[8] = {};
        if (n < nN) {
            int s0 = rp[n], s1 = rp[n + 1];
            int e = s0;
            for (; e + 4 <= s1; e += 4) {
                int sa = col[e], sb = col[e + 1], sc = col[e + 2], sd = col[e + 3];
                bf16x8 va = *(const bf16x8*)(t + (size_t)sa * D + lane * 8);
                bf16x8 vb = *(const bf16x8*)(t + (size_t)sb * D + lane * 8);
                bf16x8 vc = *(const bf16x8*)(t + (size_t)sc * D + lane * 8);
                bf16x8 vd = *(const bf16x8*)(t + (size_t)sd * D + lane * 8);
                #pragma unroll
                for (int i = 0; i < 8; ++i) {
                    acc0[i] += (float)va[i] + (float)vc[i];
                    acc1[i] += (float)vb[i] + (float)vd[i];
                }
            }
            for (; e < s1; ++e) {
                int sa = col[e];
                bf16x8 va = *(const bf16x8*)(t + (size_t)sa * D + lane * 8);
                #pragma unroll
                for (int i = 0; i < 8; ++i) acc0[i] += (float)va[i];
            }
        }
        bf16x8 o;
        #pragma unroll
        for (int i = 0; i < 8; ++i) o[i] = (__bf16)fmaxf(acc0[i] + acc1[i], 0.f);
        int P = r * 64 + ((lane + r) & 63);
        *(bf16x8*)&As[(size_t)P * 8] = o;
    }
    __syncthreads();

    floatx4 acc = {};
    for (int k0 = 0; k0 < D; k0 += 32) {
        async_cp16(B + (size_t)lane * D + k0 + w * 8, &Bs[(size_t)w * 512]);
        __syncthreads();
        int g = (k0 >> 3) + quad;
        bf16x8 af = *(const bf16x8*)&As[(size_t)(l15 * 64 + ((g + l15) & 63)) * 8];
        bf16x8 bfr = *(const bf16x8*)&Bs[(size_t)(quad * 64 + w * 16 + l15) * 8];
        acc = __builtin_amdgcn_mfma_f32_16x16x32_bf16(af, bfr, acc, 0, 0, 0);
        __syncthreads();
    }

    #pragma unroll
    for (int r = 0; r < 4; ++r) {
        int m = m0 + quad * 4 + r;
        if (m < nN)
            u[(size_t)m * DOUT + w * 16 + l15] = (__bf16)acc[r];
    }
}

// ---- propagate 64-wide + log_softmax fused: wave per node, lane = output col ----
__global__ __launch_bounds__(256) void prop2_lsm(const __bf16* __restrict__ u,
        const int* __restrict__ rp, const int* __restrict__ col,
        float* __restrict__ out, int nN) {
    int n = blockIdx.x * 4 + (threadIdx.x >> 6);
    if (n >= nN) return;
    int lane = threadIdx.x & 63;
    int s0 = rp[n], s1 = rp[n + 1];
    float a0 = 0.f, a1 = 0.f, a2 = 0.f, a3 = 0.f;
    int e = s0;
    for (; e + 4 <= s1; e += 4) {
        int sa = col[e], sb = col[e + 1], sc = col[e + 2], sd = col[e + 3];
        a0 += (float)u[(size_t)sa * DOUT + lane];
        a1 += (float)u[(size_t)sb * DOUT + lane];
        a2 += (float)u[(size_t)sc * DOUT + lane];
        a3 += (float)u[(size_t)sd * DOUT + lane];
    }
    for (; e < s1; ++e) a0 += (float)u[(size_t)col[e] * DOUT + lane];
    float v = (a0 + a2) + (a1 + a3);
    float mx = v;
    #pragma unroll
    for (int off = 32; off >= 1; off >>= 1) mx = fmaxf(mx, __shfl_xor(mx, off, 64));
    float s = expf(v - mx);
    #pragma unroll
    for (int off = 32; off >= 1; off >>= 1) s += __shfl_xor(s, off, 64);
    out[(size_t)n * DOUT + lane] = v - mx - logf(s);
}

// ---------------- launch ----------------

extern "C" void kernel_launch(void* const* d_in, const int* in_sizes, int n_in,
                              void* d_out, int out_size, void* d_ws, size_t ws_size,
                              hipStream_t stream) {
    const float* x  = (const float*)d_in[0];
    const int*   ei = (const int*)d_in[1];
    const float* W1 = (const float*)d_in[2];
    const float* W2 = (const float*)d_in[3];
    float* out = (float*)d_out;

    const int N = in_sizes[0] / D;   // 20000
    const int E = in_sizes[1] / 2;   // 160000
    const int* src = ei;
    const int* dst = ei + E;
    const int SB = (N + 1023) / 1024;

    size_t off = 0;
    auto alloc = [&](size_t bytes) -> void* {
        void* p = (char*)d_ws + off;
        off = (off + bytes + 255) & ~(size_t)255;
        return p;
    };
    const int nMeta = N + SB + 1;
    int*    meta    = (int*)alloc(sizeof(int) * (size_t)nMeta);
    int*    deg     = meta;
    int*    prefix  = meta + N;
    int*    done    = meta + N + SB;
    int*    row_ptr = (int*)alloc(sizeof(int) * (size_t)(N + 1));
    int*    cursor  = (int*)alloc(sizeof(int) * (size_t)N);
    int*    col     = (int*)alloc(sizeof(int) * (size_t)E);
    __bf16* w1b     = (__bf16*)alloc(sizeof(__bf16) * (size_t)D * D);
    __bf16* w2b     = (__bf16*)alloc(sizeof(__bf16) * (size_t)DOUT * D);
    __bf16* xb      = (__bf16*)alloc(sizeof(__bf16) * (size_t)N * D);
    __bf16* t       = (__bf16*)alloc(sizeof(__bf16) * (size_t)N * D);    // x@W1^T
    __bf16* u       = (__bf16*)alloc(sizeof(__bf16) * (size_t)N * DOUT); // relu(S t)@W2^T

    const int zeroBlocks = (nMeta + 1023) / 1024;
    const int xN8 = N * D / 8, w1N8 = D * D / 8, w2N8 = DOUT * D / 8;
    const int cvtBlocks = (xN8 + 255) / 256 + (w1N8 + 255) / 256 + (w2N8 + 255) / 256;

    // 1) prep: zero meta + bf16 conversions
    prep_kernel<<<zeroBlocks + cvtBlocks, 256, 0, stream>>>(
        meta, nMeta, zeroBlocks, x, xb, xN8, W1, w1b, w1N8, W2, w2b, w2N8);

    // 2) t = xb @ W1^T (async LDS staging) + degree histogram
    const int gemmBlocks = ((N + 127) / 128) * 4;
    gemm1_hist<<<gemmBlocks + 64, 256, 0, stream>>>(
        xb, w1b, t, N, gemmBlocks, dst, deg, E);

    // 3) fused scan + CSR fill (single done-counter handshake)
    const int fillBlocks = (E + 255) / 256;
    scanfill_kernel<<<SB + fillBlocks, 256, 0, stream>>>(
        deg, row_ptr, cursor, col, src, dst, prefix, done, N, E, SB);

    // 4) u = relu(S t) @ W2^T
    prop1_gemm2<<<(N + 15) / 16, 256, 0, stream>>>(t, row_ptr, col, w2b, u, N);

    // 5) out = lsm(S u)
    prop2_lsm<<<(N + 3) / 4, 256, 0, stream>>>(u, row_ptr, col, out, N);
}